// Round 15
// baseline (1216.358 us; speedup 1.0000x reference)
//
#include <hip/hip_runtime.h>
#include <hip/hip_bf16.h>

typedef __bf16 bf16_t;
typedef __bf16 bf16x4 __attribute__((ext_vector_type(4)));
typedef __bf16 bf16x8 __attribute__((ext_vector_type(8)));
typedef float f32x4 __attribute__((ext_vector_type(4)));

#define S_ 2048
#define D_ 4096
#define H_ 32
#define KVH_ 8
#define DH_ 128
#define HID_ 11008
#define QKV_N 6144   // 4096 q + 1024 k + 1024 v
#define GU_N 22016   // interleaved: row 2c = wg^T col c, row 2c+1 = w1^T col c

__device__ __forceinline__ void gl16(const bf16_t* g, bf16_t* l) {
  __builtin_amdgcn_global_load_lds(
      (const __attribute__((address_space(1))) unsigned int*)g,
      (__attribute__((address_space(3))) unsigned int*)l, 16, 0, 0);
}

#define VMW(N)                                          \
  asm volatile("s_waitcnt vmcnt(" #N ")" ::: "memory"); \
  __builtin_amdgcn_sched_barrier(0)

#define LGKM(N)                                           \
  asm volatile("s_waitcnt lgkmcnt(" #N ")" ::: "memory"); \
  __builtin_amdgcn_sched_barrier(0)

#define SB() __builtin_amdgcn_sched_barrier(0)

#define BAR()                          \
  asm volatile("" ::: "memory");       \
  __builtin_amdgcn_s_barrier();        \
  asm volatile("" ::: "memory")

// ---------------------------------------------------------------- RMSNorm ----
__global__ __launch_bounds__(256) void rmsnorm_kernel(
    const float* __restrict__ x, const float* __restrict__ w,
    bf16_t* __restrict__ out) {
  int row = blockIdx.x;
  const float* xr = x + (size_t)row * D_;
  float ss = 0.f;
  #pragma unroll
  for (int it = 0; it < 4; ++it) {
    int i = threadIdx.x * 4 + it * 1024;
    float4 v = *(const float4*)(xr + i);
    ss += v.x * v.x + v.y * v.y + v.z * v.z + v.w * v.w;
  }
  #pragma unroll
  for (int off = 32; off; off >>= 1) ss += __shfl_xor(ss, off);
  __shared__ float s4[4];
  if ((threadIdx.x & 63) == 0) s4[threadIdx.x >> 6] = ss;
  __syncthreads();
  float tot = s4[0] + s4[1] + s4[2] + s4[3];
  float rinv = rsqrtf(tot / (float)D_ + 1e-5f);
  bf16_t* orow = out + (size_t)row * D_;
  #pragma unroll
  for (int it = 0; it < 4; ++it) {
    int i = threadIdx.x * 4 + it * 1024;
    float4 v = *(const float4*)(xr + i);
    orow[i + 0] = (bf16_t)(v.x * rinv * w[i + 0]);
    orow[i + 1] = (bf16_t)(v.y * rinv * w[i + 1]);
    orow[i + 2] = (bf16_t)(v.z * rinv * w[i + 2]);
    orow[i + 3] = (bf16_t)(v.w * rinv * w[i + 3]);
  }
}

// -------------------- combine wo-partials (x already fused) + RMSNorm --------
// x1 = p0 + p1 ; out = rmsnorm(x1) * w   (p0 already contains +x)
__global__ __launch_bounds__(256) void combine_rms_kernel(
    const float* __restrict__ p0, const float* __restrict__ p1,
    const float* __restrict__ w, float* __restrict__ x1,
    bf16_t* __restrict__ out) {
  int row = blockIdx.x;
  size_t base = (size_t)row * D_;
  float ss = 0.f;
  float4 vals[4];
  #pragma unroll
  for (int it = 0; it < 4; ++it) {
    int i = threadIdx.x * 4 + it * 1024;
    float4 b = *(const float4*)(p0 + base + i);
    float4 c = *(const float4*)(p1 + base + i);
    float4 v;
    v.x = b.x + c.x; v.y = b.y + c.y;
    v.z = b.z + c.z; v.w = b.w + c.w;
    vals[it] = v;
    *(float4*)(x1 + base + i) = v;
    ss += v.x * v.x + v.y * v.y + v.z * v.z + v.w * v.w;
  }
  #pragma unroll
  for (int off = 32; off; off >>= 1) ss += __shfl_xor(ss, off);
  __shared__ float s4[4];
  if ((threadIdx.x & 63) == 0) s4[threadIdx.x >> 6] = ss;
  __syncthreads();
  float tot = s4[0] + s4[1] + s4[2] + s4[3];
  float rinv = rsqrtf(tot / (float)D_ + 1e-5f);
  #pragma unroll
  for (int it = 0; it < 4; ++it) {
    int i = threadIdx.x * 4 + it * 1024;
    float4 v = vals[it];
    out[base + i + 0] = (bf16_t)(v.x * rinv * w[i + 0]);
    out[base + i + 1] = (bf16_t)(v.y * rinv * w[i + 1]);
    out[base + i + 2] = (bf16_t)(v.z * rinv * w[i + 2]);
    out[base + i + 3] = (bf16_t)(v.w * rinv * w[i + 3]);
  }
}

// --------------- combine w2-partials (x1 already fused) -> d_out -------------
__global__ __launch_bounds__(256) void combine_out_kernel(
    const float* __restrict__ p0, const float* __restrict__ p1,
    float* __restrict__ outp) {
  size_t i = ((size_t)blockIdx.x * 256 + threadIdx.x) * 4;
  float4 b = *(const float4*)(p0 + i);
  float4 c = *(const float4*)(p1 + i);
  float4 v;
  v.x = b.x + c.x; v.y = b.y + c.y;
  v.z = b.z + c.z; v.w = b.w + c.w;
  *(float4*)(outp + i) = v;
}

// ------------------------------------------- weight transpose f32 -> bf16 ----
// out row index = (n0+nn)*rstride + roff  (rstride=2 interleaves wg/w1)
__device__ __forceinline__ void wtrans_body(
    const float* __restrict__ W, bf16_t* __restrict__ WT, int K, int N,
    int rstride, int roff, int bx, int by) {
  __shared__ bf16_t t[32][258];
  int k0 = bx * 32, n0 = by * 256;
  #pragma unroll
  for (int i = 0; i < 8; ++i) {
    int flat = i * 1024 + threadIdx.x * 4;
    int kk = flat >> 8, nn = flat & 255;
    float4 wv = *(const float4*)(W + (size_t)(k0 + kk) * N + n0 + nn);
    bf16_t* p = &t[kk][nn];
    p[0] = (bf16_t)wv.x; p[1] = (bf16_t)wv.y;
    p[2] = (bf16_t)wv.z; p[3] = (bf16_t)wv.w;
  }
  __syncthreads();
  int kc8 = (threadIdx.x & 3) * 8;
  #pragma unroll
  for (int i = 0; i < 4; ++i) {
    int nn = i * 64 + (threadIdx.x >> 2);
    bf16x8 vals;
    #pragma unroll
    for (int j = 0; j < 8; ++j) vals[j] = t[kc8 + j][nn];
    *(bf16x8*)(WT + ((size_t)(n0 + nn) * rstride + roff) * K + k0 + kc8) = vals;
  }
}

__global__ __launch_bounds__(256) void wtrans_kernel(
    const float* __restrict__ W, bf16_t* __restrict__ WT, int K, int N,
    int rstride, int roff) {
  wtrans_body(W, WT, K, N, rstride, roff, blockIdx.x, blockIdx.y);
}

// merged qkv weight transpose: blocks [0,2048)=wq, [2048,2560)=wk, rest=wv
__global__ __launch_bounds__(256) void wtrans_qkv_kernel(
    const float* __restrict__ wq, const float* __restrict__ wk,
    const float* __restrict__ wv, bf16_t* __restrict__ WT) {
  int id = blockIdx.x;
  if (id < 2048) {
    wtrans_body(wq, WT, D_, D_, 1, 0, id & 127, id >> 7);
  } else if (id < 2560) {
    int t = id - 2048;
    wtrans_body(wk, WT + (size_t)4096 * D_, D_, 1024, 1, 0, t & 127, t >> 7);
  } else {
    int t = id - 2560;
    wtrans_body(wv, WT + (size_t)5120 * D_, D_, 1024, 1, 0, t & 127, t >> 7);
  }
}

// merged wg|w1 interleaved transpose: blocks [0,5504)=wg(roff0), rest=w1(roff1)
__global__ __launch_bounds__(256) void wtrans_gu_kernel(
    const float* __restrict__ wg, const float* __restrict__ w1,
    bf16_t* __restrict__ WT) {
  int id = blockIdx.x;
  if (id < 5504) {
    wtrans_body(wg, WT, D_, HID_, 2, 0, id & 127, id >> 7);
  } else {
    int t = id - 5504;
    wtrans_body(w1, WT, D_, HID_, 2, 1, t & 127, t >> 7);
  }
}

// ------------------------------------- V transpose: qkv v-part -> vt[d][s] ---
__global__ __launch_bounds__(256) void vtrans_kernel(
    const bf16_t* __restrict__ qkv, bf16_t* __restrict__ vt) {
  __shared__ bf16_t t[64][72];
  int s0 = blockIdx.x * 64, d0 = blockIdx.y * 64;
  #pragma unroll
  for (int it = 0; it < 2; ++it) {
    int r = (threadIdx.x >> 3) + it * 32;
    int c = (threadIdx.x & 7) * 8;
    *(bf16x8*)&t[r][c] =
        *(const bf16x8*)(qkv + (size_t)(s0 + r) * QKV_N + 5120 + d0 + c);
  }
  __syncthreads();
  #pragma unroll
  for (int it = 0; it < 2; ++it) {
    int c = threadIdx.x & 63;
    int sb = (threadIdx.x >> 6) * 16 + it * 8;
    bf16x8 v;
    #pragma unroll
    for (int j = 0; j < 8; ++j) v[j] = t[sb + j][c];
    *(bf16x8*)(vt + (size_t)(d0 + c) * S_ + s0 + sb) = v;
  }
}

// ------------------------------------------------------------- RoPE table ----
__global__ __launch_bounds__(256) void rope_table_kernel(
    const int* __restrict__ pos_ids, float* __restrict__ cos_t,
    float* __restrict__ sin_t) {
  int idx = blockIdx.x * 256 + threadIdx.x;  // S_*64
  int s = idx >> 6, i = idx & 63;
  float pos = (float)pos_ids[s];
  float inv_freq = exp2f(-(float)i * (13.287712379549449f / 64.0f));
  float ang = pos * inv_freq;
  cos_t[idx] = cosf(ang);
  sin_t[idx] = sinf(ang);
}

// ------------------------------------------------------- 256x256 GEMM --------
// C[2048][N] = A[2048][K+] (bf16) @ BT[N][K+] (bf16)
// MODE 0: bf16 out
// MODE 2: f32 store (SPLIT partials); kz==0 adds residual cosT (f32) if set
// MODE 3: bf16 out + fused RoPE on cols < 5120 (qkv; pairs = adjacent fr lanes)
// MODE 4: fused silu(g)*u from interleaved gu cols; even lanes store h[col>>1]
// r11 structure: 1024 thr, 16 waves (4Mx4N), 64x64/wave, BK=64, dbuf,
// 1 barrier + VMW(0)/tile, zero-conflict chunk-rotation LDS.
// NOTE (r8): no extra fragment register sets — they spill. (r10/r12: barrier
// thinning and lgkmcnt group pipelines = null; LDS-fragment BW and MFMA are
// co-dominant at this tile geometry — GEMM plateau ~45% MfmaUtil.)

#define READ_A(dst, BIx, KK)                                               \
  _Pragma("unroll") for (int m = 0; m < 4; ++m)                            \
    dst[m] = *(const bf16x8*)&lds[BIx][0][KK]                              \
        [(wr * 64 + m * 16 + fr) * 32 + rc * 8];

#define READ_B(dst, BIx, KK)                                               \
  _Pragma("unroll") for (int n = 0; n < 4; ++n)                            \
    dst[n] = *(const bf16x8*)&lds[BIx][1][KK]                              \
        [(wc * 64 + n * 16 + fr) * 32 + rc * 8];

#define MFMA16(aS, bS)                                                     \
  __builtin_amdgcn_s_setprio(1);                                           \
  _Pragma("unroll") for (int m = 0; m < 4; ++m)                            \
    _Pragma("unroll") for (int n = 0; n < 4; ++n)                          \
      acc[m][n] = __builtin_amdgcn_mfma_f32_16x16x32_bf16(                 \
          aS[m], bS[n], acc[m][n], 0, 0, 0);                               \
  __builtin_amdgcn_s_setprio(0);

template <int MODE, int SPLIT>
__global__ __launch_bounds__(1024, 4) void gemm256_kernel(
    const bf16_t* __restrict__ A, int lda, const bf16_t* __restrict__ BT,
    int ldb, void* __restrict__ Cout, int ldc, int K,
    const float* __restrict__ cosT, const float* __restrict__ sinT) {
  // [buf][A=0/B=1][kk][256 rows * 32 elems] = 128 KiB
  __shared__ __align__(16) bf16_t lds[2][2][2][256 * 32];

  const int tid = threadIdx.x;
  const int lane = tid & 63;
  const int wid = tid >> 6;           // 0..15
  const int wr = wid >> 2;            // 0..3 (M quarter)
  const int wc = wid & 3;             // 0..3 (N quarter)
  const int g = lane >> 4, fr = lane & 15;
  const int rc = (g + ((fr >> 1) & 3)) & 3;   // rotated read-chunk slot

  const int nwg = gridDim.x;
  const int orig = blockIdx.x;
  int wg = (orig & 7) * (nwg >> 3) + (orig >> 3);
  int kz = 0;
  if constexpr (SPLIT) {
    const int half = nwg >> 1;
    kz = wg >= half;
    wg -= kz * half;
  }
  const int bx = wg & 7;
  const int by = wg >> 3;
  const size_t row0 = (size_t)bx * 256, col0 = (size_t)by * 256;

  // staging: row-linear source, chunk rotated by (row>>1); row = tid>>2 (0..255)
  const int srow = tid >> 2;
  const int schunk = ((tid & 3) - ((tid >> 3) & 3)) & 3;

  const size_t lda2 = (size_t)lda * 2, ldb2 = (size_t)ldb * 2;
  const size_t kzoff = (size_t)kz * K * 2;
  const char* aB =
      (const char*)A + (row0 + srow) * lda2 + schunk * 16 + kzoff;
  const char* bB =
      (const char*)BT + (col0 + srow) * ldb2 + schunk * 16 + kzoff;

  auto stage = [&](int bi, int ab, int kk, int kt) {
    const char* base = ab ? bB : aB;
    gl16((const bf16_t*)(base + (size_t)kt * 128 + kk * 64),
         &lds[bi][ab][kk][tid * 8]);
  };

  f32x4 acc[4][4] = {};
  bf16x8 aF[4], bF[4];
  const int NT = K / 64;

  // prologue: tile0 -> buf0
  stage(0, 0, 0, 0); stage(0, 1, 0, 0);
  stage(0, 0, 1, 0); stage(0, 1, 1, 0);
  VMW(0);
  BAR();

  for (int T = 0; T < NT; ++T) {
    const int BI = T & 1;
    const int Tp1 = T + 1 < NT;
    if (Tp1) {  // next tile -> other buffer; readers finished at T-1's barrier
      stage(BI ^ 1, 0, 0, T + 1); stage(BI ^ 1, 1, 0, T + 1);
      stage(BI ^ 1, 0, 1, T + 1); stage(BI ^ 1, 1, 1, T + 1);
    }
    READ_A(aF, BI, 0); READ_B(bF, BI, 0);
    LGKM(0);
    MFMA16(aF, bF);
    READ_A(aF, BI, 1); READ_B(bF, BI, 1);
    LGKM(0);
    MFMA16(aF, bF);
    VMW(0);   // T+1's 4 loads resident (issued a full tile of compute ago)
    BAR();
  }

  // epilogue
  float* fOut = (float*)Cout + (size_t)kz * 2048 * ldc;
  #pragma unroll
  for (int m = 0; m < 4; ++m)
    #pragma unroll
    for (int n = 0; n < 4; ++n)
      #pragma unroll
      for (int r = 0; r < 4; ++r) {
        size_t row = row0 + wr * 64 + m * 16 + g * 4 + r;
        size_t col = col0 + wc * 64 + n * 16 + fr;
        float val = acc[m][n][r];
        if constexpr (MODE == 0) {
          ((bf16_t*)Cout)[row * ldc + col] = (bf16_t)val;
        } else if constexpr (MODE == 2) {
          if (cosT != nullptr && kz == 0) val += cosT[row * ldc + col];
          fOut[row * ldc + col] = val;
        } else if constexpr (MODE == 3) {
          // fused RoPE: pairs (2i,2i+1) are adjacent fr lanes
          float p = __shfl_xor(val, 1);
          if ((int)col < 5120) {
            int i = ((int)col & 127) >> 1;
            float c = cosT[row * 64 + i], s = sinT[row * 64 + i];
            val = (fr & 1) ? (p * s + val * c) : (val * c - p * s);
          }
          ((bf16_t*)Cout)[row * ldc + col] = (bf16_t)val;
        } else {
          // MODE 4: interleaved gu -> h = silu(g)*u, even lanes store col>>1
          float p = __shfl_xor(val, 1);
          if (!(fr & 1)) {
            float gv = val;
            float hv = gv / (1.f + __expf(-gv)) * p;
            ((bf16_t*)Cout)[row * ldc + (col >> 1)] = (bf16_t)hv;
          }
        }
      }
}

// ------------------------------------------------------- flash attention -----
// grid (32 qb, 32 h), 4 waves (r13 version). K and V^T staged via
// global_load_lds into lane-ordered fragment blocks (zero-conflict
// ds_read_b128), double-buffered with counted vmcnt(8).
__global__ __launch_bounds__(256, 2) void attn_kernel(
    const bf16_t* __restrict__ qkv, const bf16_t* __restrict__ vt,
    bf16_t* __restrict__ o) {
  int h = blockIdx.y;
  int qb = (S_ / 64 - 1) - blockIdx.x;  // longest blocks dispatch first
  int kvh = h >> 2;
  int tid = threadIdx.x;
  int wid = tid >> 6, lane = tid & 63;
  int g = lane >> 4, fr = lane & 15;

  __shared__ __align__(16) bf16_t kfl[2][8192];
  __shared__ __align__(16) bf16_t vfl[2][8192];
  __shared__ __align__(16) bf16_t p_lds[4][16][72];

  const int fr_s = (tid >> 2) & 15, g_s = tid & 3;
  const int kcw = (tid >> 6) & 3;
  const int kc2w = (tid >> 6) & 1;
  const int nhi = tid >> 7;
  const bf16_t* kSrc = qkv + (size_t)fr_s * QKV_N + 4096 + kvh * 128 +
                       (kcw * 4 + g_s) * 8;
  const bf16_t* vSrc = vt + ((size_t)kvh * 128 + nhi * 16 + fr_s) * S_ +
                       (kc2w * 4 + g_s) * 8;

  auto stage = [&](int bi, int t) {
    size_t kv0 = (size_t)t * 64;
    #pragma unroll
    for (int i = 0; i < 4; ++i)
      gl16(kSrc + (kv0 + i * 16) * QKV_N, &kfl[bi][(i * 256 + tid) * 8]);
    #pragma unroll
    for (int i = 0; i < 4; ++i)
      gl16(vSrc + (size_t)i * 32 * S_ + kv0, &vfl[bi][(i * 256 + tid) * 8]);
  };

  int q0w = qb * 64 + wid * 16;
  bf16x8 q_frag[4];
  const bf16_t* qptr = qkv + (size_t)(q0w + fr) * QKV_N + h * 128;
  #pragma unroll
  for (int kc = 0; kc < 4; ++kc)
    q_frag[kc] = *(const bf16x8*)(qptr + kc * 32 + g * 8);
  VMW(0);  // q_frag landed; keep manual vmcnt accounting exact

  stage(0, 0);

  f32x4 o_frag[8] = {};
  float m_run[4], l_run[4];
  #pragma unroll
  for (int r = 0; r < 4; ++r) { m_run[r] = -1e30f; l_run[r] = 0.f; }

  const float sc = 0.08838834764831845f * 1.4426950408889634f;

  for (int t = 0; t <= qb; ++t) {
    int cur = t & 1;
    int kv0 = t * 64;
    if (t < qb) {
      stage(cur ^ 1, t + 1);
      VMW(8);
    } else {
      VMW(0);
    }
    BAR();

    f32x4 sfr[4];
    #pragma unroll
    for (int nf = 0; nf < 4; ++nf) {
      f32x4 acc = {};
      #pragma unroll
      for (int kc = 0; kc < 4; ++kc) {
        bf16x8 kf =
            *(const bf16x8*)&kfl[cur][(nf * 256 + kc * 64 + fr * 4 + g) * 8];
        acc = __builtin_amdgcn_mfma_f32_16x16x32_bf16(q_frag[kc], kf, acc, 0, 0, 0);
      }
      sfr[nf] = acc;
    }

    bool diag = (t == qb);
    float mtile[4];
    #pragma unroll
    for (int r = 0; r < 4; ++r) mtile[r] = -1e30f;
    #pragma unroll
    for (int nf = 0; nf < 4; ++nf)
      #pragma unroll
      for (int r = 0; r < 4; ++r) {
        if (diag) {
          int kvg = kv0 + nf * 16 + fr;
          int qg = q0w + 4 * g + r;
          if (kvg > qg) sfr[nf][r] = -1e30f;
        }
        mtile[r] = fmaxf(mtile[r], sfr[nf][r]);
      }
    #pragma unroll
    for (int r = 0; r < 4; ++r) {
      float mv = mtile[r];
      mv = fmaxf(mv, __shfl_xor(mv, 1));
      mv = fmaxf(mv, __shfl_xor(mv, 2));
      mv = fmaxf(mv, __shfl_xor(mv, 4));
      mv = fmaxf(mv, __shfl_xor(mv, 8));
      mtile[r] = mv;
    }
    float alpha[4];
    #pragma unroll
    for (int r = 0; r < 4; ++r) {
      float m_new = fmaxf(m_run[r], mtile[r]);
      alpha[r] = exp2f((m_run[r] - m_new) * sc);
      m_run[r] = m_new;
    }
    float lsum[4] = {0.f, 0.f, 0.f, 0.f};
    #pragma unroll
    for (int nf = 0; nf < 4; ++nf)
      #pragma unroll
      for (int r = 0; r < 4; ++r) {
        float p = exp2f((sfr[nf][r] - m_run[r]) * sc);
        sfr[nf][r] = p;
        lsum[r] += p;
      }
    #pragma unroll
    for (int r = 0; r < 4; ++r) {
      float lv = lsum[r];
      lv += __shfl_xor(lv, 1);
      lv += __shfl_xor(lv, 2);
      lv += __shfl_xor(lv, 4);
      lv += __shfl_xor(lv, 8);
      l_run[r] = l_run[r] * alpha[r] + lv;
    }
    #pragma unroll
    for (int nfo = 0; nfo < 8; ++nfo)
      #pragma unroll
      for (int r = 0; r < 4; ++r) o_frag[nfo][r] *= alpha[r];

    #pragma unroll
    for (int nf = 0; nf < 4; ++nf)
      #pragma unroll
      for (int r = 0; r < 4; ++r)
        p_lds[wid][4 * g + r][nf * 16 + fr] = (bf16_t)sfr[nf][r];

    #pragma unroll
    for (int kc2 = 0; kc2 < 2; ++kc2) {
      bf16x8 pf = *(const bf16x8*)&p_lds[wid][fr][kc2 * 32 + g * 8];
      #pragma unroll
      for (int nfo = 0; nfo < 8; ++nfo) {
        bf16x8 vf =
            *(const bf16x8*)&vfl[cur][(nfo * 128 + kc2 * 64 + fr * 4 + g) * 8];
        o_frag[nfo] = __builtin_amdgcn_mfma_f32_16x16x32_bf16(pf, vf, o_frag[nfo], 0, 0, 0);
      }
    }
    BAR();
  }

  #pragma unroll
  for (int nfo = 0; nfo < 8; ++nfo)
    #pragma unroll
    for (int r = 0; r < 4; ++r) {
      int qg = q0w + 4 * g + r;
      float val = o_frag[nfo][r] / l_run[r];
      o[(size_t)qg * (H_ * DH_) + h * DH_ + nfo * 16 + fr] = (bf16_t)val;
    }
}

// ---------------------------------------------------------------- launch -----
extern "C" void kernel_launch(void* const* d_in, const int* in_sizes, int n_in,
                              void* d_out, int out_size, void* d_ws,
                              size_t ws_size, hipStream_t stream) {
  const float* x = (const float*)d_in[0];
  const int* pos = (const int*)d_in[1];
  const float* ln_w = (const float*)d_in[2];
  const float* ffln_w = (const float*)d_in[3];
  const float* wq = (const float*)d_in[4];
  const float* wk = (const float*)d_in[5];
  const float* wv = (const float*)d_in[6];
  const float* wo = (const float*)d_in[7];
  const float* wg = (const float*)d_in[8];
  const float* w1 = (const float*)d_in[9];
  const float* w2 = (const float*)d_in[10];

  char* ws = (char*)d_ws;
  size_t off = 0;
  auto alloc = [&](size_t bytes) {
    size_t o = off;
    off = (off + bytes + 255) & ~(size_t)255;
    return o;
  };
  bf16_t* Wbuf = (bf16_t*)(ws + alloc((size_t)GU_N * D_ * 2));  // ~172MB shared
  bf16_t* nbuf = (bf16_t*)(ws + alloc((size_t)S_ * D_ * 2));    // a / attn / b
  bf16_t* qkv  = (bf16_t*)(ws + alloc((size_t)S_ * QKV_N * 2));
  float*  x1   = (float*)(ws + alloc((size_t)S_ * D_ * 4));
  bf16_t* h    = (bf16_t*)(ws + alloc((size_t)S_ * HID_ * 2));  // silu(g)*u
  bf16_t* vtb  = (bf16_t*)(ws + alloc((size_t)KVH_ * DH_ * S_ * 2));  // 4MB
  float*  cos_t = (float*)(ws + alloc((size_t)S_ * 64 * 4));
  float*  sin_t = (float*)(ws + alloc((size_t)S_ * 64 * 4));
  // split-K partial buffers in the unused tail of Wbuf: partials (96..160MB)
  // only live while weights <= 90MB (wo / w2); wg|w1's 180MB never coexists.
  float* part = (float*)((char*)Wbuf + ((size_t)96 << 20));  // 2 x 32MB

  // 1. a = rmsnorm(x)
  rmsnorm_kernel<<<S_, 256, 0, stream>>>(x, ln_w, nbuf);
  // 2. W_qkv^T (bf16, merged): rows 0..4095=wq^T, 4096..5119=wk^T, 5120+=wv^T
  wtrans_qkv_kernel<<<3072, 256, 0, stream>>>(wq, wk, wv, Wbuf);
  rope_table_kernel<<<(S_ * 64) / 256, 256, 0, stream>>>(pos, cos_t, sin_t);
  // 3. qkv = a @ Wqkv with fused RoPE on q,k columns
  gemm256_kernel<3, 0><<<dim3((S_ / 256) * (QKV_N / 256)), 1024, 0, stream>>>(
      nbuf, D_, Wbuf, D_, qkv, QKV_N, D_, cos_t, sin_t);
  // 4. V^T
  vtrans_kernel<<<dim3(S_ / 64, (KVH_ * DH_) / 64), 256, 0, stream>>>(qkv, vtb);
  // 5. attention -> nbuf
  attn_kernel<<<dim3(S_ / 64, H_), 256, 0, stream>>>(qkv, vtb, nbuf);
  // 6. partials = attn @ wo (split-K 2x2048, 256 blocks); kz=0 adds x
  wtrans_kernel<<<dim3(D_ / 32, D_ / 256), 256, 0, stream>>>(
      wo, Wbuf, D_, D_, 1, 0);
  gemm256_kernel<2, 1><<<dim3((S_ / 256) * (D_ / 256) * 2), 1024, 0, stream>>>(
      nbuf, D_, Wbuf, D_, part, D_, 2048, x, nullptr);
  // 7. x1 = p0 + p1 ; b = rmsnorm(x1)
  combine_rms_kernel<<<S_, 256, 0, stream>>>(
      part, part + (size_t)S_ * D_, ffln_w, x1, nbuf);
  // 8. h = silu(b@wg) * (b@w1), interleaved weights (merged wtrans) + fusion
  wtrans_gu_kernel<<<11008, 256, 0, stream>>>(wg, w1, Wbuf);
  gemm256_kernel<4, 0><<<dim3((S_ / 256) * (GU_N / 256)), 1024, 0, stream>>>(
      nbuf, D_, Wbuf, D_, h, HID_, D_, nullptr, nullptr);
  // 9. partials = h @ w2 (split-K 2x5504, 256 blocks); kz=0 adds x1
  wtrans_kernel<<<dim3(HID_ / 32, D_ / 256), 256, 0, stream>>>(
      w2, Wbuf, HID_, D_, 1, 0);
  gemm256_kernel<2, 1><<<dim3((S_ / 256) * (D_ / 256) * 2), 1024, 0, stream>>>(
      h, HID_, Wbuf, HID_, part, D_, 5504, x1, nullptr);
  // 10. out = p0 + p1
  combine_out_kernel<<<(S_ * D_ / 4) / 256, 256, 0, stream>>>(
      part, part + (size_t)S_ * D_, (float*)d_out);
}

// Round 16
// 1182.244 us; speedup vs baseline: 1.0289x; 1.0289x over previous
//
#include <hip/hip_runtime.h>
#include <hip/hip_bf16.h>

typedef __bf16 bf16_t;
typedef __bf16 bf16x4 __attribute__((ext_vector_type(4)));
typedef __bf16 bf16x8 __attribute__((ext_vector_type(8)));
typedef float f32x4 __attribute__((ext_vector_type(4)));

#define S_ 2048
#define D_ 4096
#define H_ 32
#define KVH_ 8
#define DH_ 128
#define HID_ 11008
#define QKV_N 6144   // 4096 q + 1024 k + 1024 v
#define GU_N 22016   // interleaved: row 2c = wg^T col c, row 2c+1 = w1^T col c

__device__ __forceinline__ void gl16(const bf16_t* g, bf16_t* l) {
  __builtin_amdgcn_global_load_lds(
      (const __attribute__((address_space(1))) unsigned int*)g,
      (__attribute__((address_space(3))) unsigned int*)l, 16, 0, 0);
}

#define VMW(N)                                          \
  asm volatile("s_waitcnt vmcnt(" #N ")" ::: "memory"); \
  __builtin_amdgcn_sched_barrier(0)

#define LGKM(N)                                           \
  asm volatile("s_waitcnt lgkmcnt(" #N ")" ::: "memory"); \
  __builtin_amdgcn_sched_barrier(0)

#define SB() __builtin_amdgcn_sched_barrier(0)

#define BAR()                          \
  asm volatile("" ::: "memory");       \
  __builtin_amdgcn_s_barrier();        \
  asm volatile("" ::: "memory")

// ---------------------------------------------------------------- RMSNorm ----
__global__ __launch_bounds__(256) void rmsnorm_kernel(
    const float* __restrict__ x, const float* __restrict__ w,
    bf16_t* __restrict__ out) {
  int row = blockIdx.x;
  const float* xr = x + (size_t)row * D_;
  float ss = 0.f;
  #pragma unroll
  for (int it = 0; it < 4; ++it) {
    int i = threadIdx.x * 4 + it * 1024;
    float4 v = *(const float4*)(xr + i);
    ss += v.x * v.x + v.y * v.y + v.z * v.z + v.w * v.w;
  }
  #pragma unroll
  for (int off = 32; off; off >>= 1) ss += __shfl_xor(ss, off);
  __shared__ float s4[4];
  if ((threadIdx.x & 63) == 0) s4[threadIdx.x >> 6] = ss;
  __syncthreads();
  float tot = s4[0] + s4[1] + s4[2] + s4[3];
  float rinv = rsqrtf(tot / (float)D_ + 1e-5f);
  bf16_t* orow = out + (size_t)row * D_;
  #pragma unroll
  for (int it = 0; it < 4; ++it) {
    int i = threadIdx.x * 4 + it * 1024;
    float4 v = *(const float4*)(xr + i);
    orow[i + 0] = (bf16_t)(v.x * rinv * w[i + 0]);
    orow[i + 1] = (bf16_t)(v.y * rinv * w[i + 1]);
    orow[i + 2] = (bf16_t)(v.z * rinv * w[i + 2]);
    orow[i + 3] = (bf16_t)(v.w * rinv * w[i + 3]);
  }
}

// ----------------------- combine wo-partials + residual + RMSNorm ------------
__global__ __launch_bounds__(256) void combine_rms_kernel(
    const float* __restrict__ x, const float* __restrict__ p0,
    const float* __restrict__ p1, const float* __restrict__ w,
    float* __restrict__ x1, bf16_t* __restrict__ out) {
  int row = blockIdx.x;
  size_t base = (size_t)row * D_;
  float ss = 0.f;
  float4 vals[4];
  #pragma unroll
  for (int it = 0; it < 4; ++it) {
    int i = threadIdx.x * 4 + it * 1024;
    float4 a = *(const float4*)(x + base + i);
    float4 b = *(const float4*)(p0 + base + i);
    float4 c = *(const float4*)(p1 + base + i);
    float4 v;
    v.x = a.x + b.x + c.x; v.y = a.y + b.y + c.y;
    v.z = a.z + b.z + c.z; v.w = a.w + b.w + c.w;
    vals[it] = v;
    *(float4*)(x1 + base + i) = v;
    ss += v.x * v.x + v.y * v.y + v.z * v.z + v.w * v.w;
  }
  #pragma unroll
  for (int off = 32; off; off >>= 1) ss += __shfl_xor(ss, off);
  __shared__ float s4[4];
  if ((threadIdx.x & 63) == 0) s4[threadIdx.x >> 6] = ss;
  __syncthreads();
  float tot = s4[0] + s4[1] + s4[2] + s4[3];
  float rinv = rsqrtf(tot / (float)D_ + 1e-5f);
  #pragma unroll
  for (int it = 0; it < 4; ++it) {
    int i = threadIdx.x * 4 + it * 1024;
    float4 v = vals[it];
    out[base + i + 0] = (bf16_t)(v.x * rinv * w[i + 0]);
    out[base + i + 1] = (bf16_t)(v.y * rinv * w[i + 1]);
    out[base + i + 2] = (bf16_t)(v.z * rinv * w[i + 2]);
    out[base + i + 3] = (bf16_t)(v.w * rinv * w[i + 3]);
  }
}

// ----------------------------- combine w2-partials + residual -> d_out -------
__global__ __launch_bounds__(256) void combine_out_kernel(
    const float* __restrict__ x1, const float* __restrict__ p0,
    const float* __restrict__ p1, float* __restrict__ outp) {
  size_t i = ((size_t)blockIdx.x * 256 + threadIdx.x) * 4;
  float4 a = *(const float4*)(x1 + i);
  float4 b = *(const float4*)(p0 + i);
  float4 c = *(const float4*)(p1 + i);
  float4 v;
  v.x = a.x + b.x + c.x; v.y = a.y + b.y + c.y;
  v.z = a.z + b.z + c.z; v.w = a.w + b.w + c.w;
  *(float4*)(outp + i) = v;
}

// ------------------------------------------- weight transpose f32 -> bf16 ----
// out row index = (n0+nn)*rstride + roff  (rstride=2 interleaves wg/w1)
__global__ __launch_bounds__(256) void wtrans_kernel(
    const float* __restrict__ W, bf16_t* __restrict__ WT, int K, int N,
    int rstride, int roff) {
  __shared__ bf16_t t[32][258];
  int k0 = blockIdx.x * 32, n0 = blockIdx.y * 256;
  #pragma unroll
  for (int i = 0; i < 8; ++i) {
    int flat = i * 1024 + threadIdx.x * 4;
    int kk = flat >> 8, nn = flat & 255;
    float4 wv = *(const float4*)(W + (size_t)(k0 + kk) * N + n0 + nn);
    bf16_t* p = &t[kk][nn];
    p[0] = (bf16_t)wv.x; p[1] = (bf16_t)wv.y;
    p[2] = (bf16_t)wv.z; p[3] = (bf16_t)wv.w;
  }
  __syncthreads();
  int kc8 = (threadIdx.x & 3) * 8;
  #pragma unroll
  for (int i = 0; i < 4; ++i) {
    int nn = i * 64 + (threadIdx.x >> 2);
    bf16x8 vals;
    #pragma unroll
    for (int j = 0; j < 8; ++j) vals[j] = t[kc8 + j][nn];
    *(bf16x8*)(WT + ((size_t)(n0 + nn) * rstride + roff) * K + k0 + kc8) = vals;
  }
}

// ------------------------------------- V transpose: qkv v-part -> vt[d][s] ---
__global__ __launch_bounds__(256) void vtrans_kernel(
    const bf16_t* __restrict__ qkv, bf16_t* __restrict__ vt) {
  __shared__ bf16_t t[64][72];
  int s0 = blockIdx.x * 64, d0 = blockIdx.y * 64;
  #pragma unroll
  for (int it = 0; it < 2; ++it) {
    int r = (threadIdx.x >> 3) + it * 32;
    int c = (threadIdx.x & 7) * 8;
    *(bf16x8*)&t[r][c] =
        *(const bf16x8*)(qkv + (size_t)(s0 + r) * QKV_N + 5120 + d0 + c);
  }
  __syncthreads();
  #pragma unroll
  for (int it = 0; it < 2; ++it) {
    int c = threadIdx.x & 63;
    int sb = (threadIdx.x >> 6) * 16 + it * 8;
    bf16x8 v;
    #pragma unroll
    for (int j = 0; j < 8; ++j) v[j] = t[sb + j][c];
    *(bf16x8*)(vt + (size_t)(d0 + c) * S_ + s0 + sb) = v;
  }
}

// ------------------------------------------------------------- RoPE table ----
__global__ __launch_bounds__(256) void rope_table_kernel(
    const int* __restrict__ pos_ids, float* __restrict__ cos_t,
    float* __restrict__ sin_t) {
  int idx = blockIdx.x * 256 + threadIdx.x;  // S_*64
  int s = idx >> 6, i = idx & 63;
  float pos = (float)pos_ids[s];
  float inv_freq = exp2f(-(float)i * (13.287712379549449f / 64.0f));
  float ang = pos * inv_freq;
  cos_t[idx] = cosf(ang);
  sin_t[idx] = sinf(ang);
}

// ------------------------------------------------------- 256x256 GEMM --------
// C[2048][N] = A[2048][K+] (bf16) @ BT[N][K+] (bf16)
// MODE 0: bf16 out
// MODE 2: f32 plain store (SPLIT partials)
// MODE 3: bf16 out + fused RoPE on cols < 5120 (qkv; pairs = adjacent fr lanes)
// MODE 4: fused silu(g)*u from interleaved gu cols; even lanes store h[col>>1]
// r11 structure: 1024 thr, 16 waves (4Mx4N), 64x64/wave, BK=64, dbuf,
// 1 barrier + VMW(0)/tile, zero-conflict chunk-rotation LDS.
// NOTE (r8): no extra fragment register sets — they spill. (r10/r12: barrier
// thinning and lgkmcnt group pipelines = null; LDS-fragment BW and MFMA are
// co-dominant at this tile geometry — GEMM plateau ~45% MfmaUtil.)

#define READ_A(dst, BIx, KK)                                               \
  _Pragma("unroll") for (int m = 0; m < 4; ++m)                            \
    dst[m] = *(const bf16x8*)&lds[BIx][0][KK]                              \
        [(wr * 64 + m * 16 + fr) * 32 + rc * 8];

#define READ_B(dst, BIx, KK)                                               \
  _Pragma("unroll") for (int n = 0; n < 4; ++n)                            \
    dst[n] = *(const bf16x8*)&lds[BIx][1][KK]                              \
        [(wc * 64 + n * 16 + fr) * 32 + rc * 8];

#define MFMA16(aS, bS)                                                     \
  __builtin_amdgcn_s_setprio(1);                                           \
  _Pragma("unroll") for (int m = 0; m < 4; ++m)                            \
    _Pragma("unroll") for (int n = 0; n < 4; ++n)                          \
      acc[m][n] = __builtin_amdgcn_mfma_f32_16x16x32_bf16(                 \
          aS[m], bS[n], acc[m][n], 0, 0, 0);                               \
  __builtin_amdgcn_s_setprio(0);

template <int MODE, int SPLIT>
__global__ __launch_bounds__(1024, 4) void gemm256_kernel(
    const bf16_t* __restrict__ A, int lda, const bf16_t* __restrict__ BT,
    int ldb, void* __restrict__ Cout, int ldc, int K,
    const float* __restrict__ cosT, const float* __restrict__ sinT) {
  // [buf][A=0/B=1][kk][256 rows * 32 elems] = 128 KiB
  __shared__ __align__(16) bf16_t lds[2][2][2][256 * 32];

  const int tid = threadIdx.x;
  const int lane = tid & 63;
  const int wid = tid >> 6;           // 0..15
  const int wr = wid >> 2;            // 0..3 (M quarter)
  const int wc = wid & 3;             // 0..3 (N quarter)
  const int g = lane >> 4, fr = lane & 15;
  const int rc = (g + ((fr >> 1) & 3)) & 3;   // rotated read-chunk slot

  const int nwg = gridDim.x;
  const int orig = blockIdx.x;
  int wg = (orig & 7) * (nwg >> 3) + (orig >> 3);
  int kz = 0;
  if constexpr (SPLIT) {
    const int half = nwg >> 1;
    kz = wg >= half;
    wg -= kz * half;
  }
  const int bx = wg & 7;
  const int by = wg >> 3;
  const size_t row0 = (size_t)bx * 256, col0 = (size_t)by * 256;

  // staging: row-linear source, chunk rotated by (row>>1); row = tid>>2 (0..255)
  const int srow = tid >> 2;
  const int schunk = ((tid & 3) - ((tid >> 3) & 3)) & 3;

  const size_t lda2 = (size_t)lda * 2, ldb2 = (size_t)ldb * 2;
  const size_t kzoff = (size_t)kz * K * 2;
  const char* aB =
      (const char*)A + (row0 + srow) * lda2 + schunk * 16 + kzoff;
  const char* bB =
      (const char*)BT + (col0 + srow) * ldb2 + schunk * 16 + kzoff;

  auto stage = [&](int bi, int ab, int kk, int kt) {
    const char* base = ab ? bB : aB;
    gl16((const bf16_t*)(base + (size_t)kt * 128 + kk * 64),
         &lds[bi][ab][kk][tid * 8]);
  };

  f32x4 acc[4][4] = {};
  bf16x8 aF[4], bF[4];
  const int NT = K / 64;

  // prologue: tile0 -> buf0
  stage(0, 0, 0, 0); stage(0, 1, 0, 0);
  stage(0, 0, 1, 0); stage(0, 1, 1, 0);
  VMW(0);
  BAR();

  for (int T = 0; T < NT; ++T) {
    const int BI = T & 1;
    const int Tp1 = T + 1 < NT;
    if (Tp1) {  // next tile -> other buffer; readers finished at T-1's barrier
      stage(BI ^ 1, 0, 0, T + 1); stage(BI ^ 1, 1, 0, T + 1);
      stage(BI ^ 1, 0, 1, T + 1); stage(BI ^ 1, 1, 1, T + 1);
    }
    READ_A(aF, BI, 0); READ_B(bF, BI, 0);
    LGKM(0);
    MFMA16(aF, bF);
    READ_A(aF, BI, 1); READ_B(bF, BI, 1);
    LGKM(0);
    MFMA16(aF, bF);
    VMW(0);   // T+1's 4 loads resident (issued a full tile of compute ago)
    BAR();
  }

  // epilogue
  float* fOut = (float*)Cout + (size_t)kz * 2048 * ldc;
  #pragma unroll
  for (int m = 0; m < 4; ++m)
    #pragma unroll
    for (int n = 0; n < 4; ++n)
      #pragma unroll
      for (int r = 0; r < 4; ++r) {
        size_t row = row0 + wr * 64 + m * 16 + g * 4 + r;
        size_t col = col0 + wc * 64 + n * 16 + fr;
        float val = acc[m][n][r];
        if constexpr (MODE == 0) {
          ((bf16_t*)Cout)[row * ldc + col] = (bf16_t)val;
        } else if constexpr (MODE == 2) {
          fOut[row * ldc + col] = val;
        } else if constexpr (MODE == 3) {
          // fused RoPE: pairs (2i,2i+1) are adjacent fr lanes
          float p = __shfl_xor(val, 1);
          if ((int)col < 5120) {
            int i = ((int)col & 127) >> 1;
            float c = cosT[row * 64 + i], s = sinT[row * 64 + i];
            val = (fr & 1) ? (p * s + val * c) : (val * c - p * s);
          }
          ((bf16_t*)Cout)[row * ldc + col] = (bf16_t)val;
        } else {
          // MODE 4: interleaved gu -> h = silu(g)*u, even lanes store col>>1
          float p = __shfl_xor(val, 1);
          if (!(fr & 1)) {
            float gv = val;
            float hv = gv / (1.f + __expf(-gv)) * p;
            ((bf16_t*)Cout)[row * ldc + (col >> 1)] = (bf16_t)hv;
          }
        }
      }
}

// ------------------------------------------------------- flash attention -----
// grid (32 qb, 32 h), 4 waves. K and V^T staged via global_load_lds into
// lane-ordered fragment blocks (zero-conflict ds_read_b128), double-buffered
// with counted vmcnt(8). V^T comes from the pre-transposed vt buffer.
__global__ __launch_bounds__(256, 2) void attn_kernel(
    const bf16_t* __restrict__ qkv, const bf16_t* __restrict__ vt,
    bf16_t* __restrict__ o) {
  int h = blockIdx.y;
  int qb = (S_ / 64 - 1) - blockIdx.x;  // longest blocks dispatch first
  int kvh = h >> 2;
  int tid = threadIdx.x;
  int wid = tid >> 6, lane = tid & 63;
  int g = lane >> 4, fr = lane & 15;

  __shared__ __align__(16) bf16_t kfl[2][8192];
  __shared__ __align__(16) bf16_t vfl[2][8192];
  __shared__ __align__(16) bf16_t p_lds[4][16][72];

  const int fr_s = (tid >> 2) & 15, g_s = tid & 3;
  const int kcw = (tid >> 6) & 3;
  const int kc2w = (tid >> 6) & 1;
  const int nhi = tid >> 7;
  const bf16_t* kSrc = qkv + (size_t)fr_s * QKV_N + 4096 + kvh * 128 +
                       (kcw * 4 + g_s) * 8;
  const bf16_t* vSrc = vt + ((size_t)kvh * 128 + nhi * 16 + fr_s) * S_ +
                       (kc2w * 4 + g_s) * 8;

  auto stage = [&](int bi, int t) {
    size_t kv0 = (size_t)t * 64;
    #pragma unroll
    for (int i = 0; i < 4; ++i)
      gl16(kSrc + (kv0 + i * 16) * QKV_N, &kfl[bi][(i * 256 + tid) * 8]);
    #pragma unroll
    for (int i = 0; i < 4; ++i)
      gl16(vSrc + (size_t)i * 32 * S_ + kv0, &vfl[bi][(i * 256 + tid) * 8]);
  };

  int q0w = qb * 64 + wid * 16;
  bf16x8 q_frag[4];
  const bf16_t* qptr = qkv + (size_t)(q0w + fr) * QKV_N + h * 128;
  #pragma unroll
  for (int kc = 0; kc < 4; ++kc)
    q_frag[kc] = *(const bf16x8*)(qptr + kc * 32 + g * 8);
  VMW(0);  // q_frag landed; keep manual vmcnt accounting exact

  stage(0, 0);

  f32x4 o_frag[8] = {};
  float m_run[4], l_run[4];
  #pragma unroll
  for (int r = 0; r < 4; ++r) { m_run[r] = -1e30f; l_run[r] = 0.f; }

  const float sc = 0.08838834764831845f * 1.4426950408889634f;

  for (int t = 0; t <= qb; ++t) {
    int cur = t & 1;
    int kv0 = t * 64;
    if (t < qb) {
      stage(cur ^ 1, t + 1);
      VMW(8);
    } else {
      VMW(0);
    }
    BAR();

    f32x4 sfr[4];
    #pragma unroll
    for (int nf = 0; nf < 4; ++nf) {
      f32x4 acc = {};
      #pragma unroll
      for (int kc = 0; kc < 4; ++kc) {
        bf16x8 kf =
            *(const bf16x8*)&kfl[cur][(nf * 256 + kc * 64 + fr * 4 + g) * 8];
        acc = __builtin_amdgcn_mfma_f32_16x16x32_bf16(q_frag[kc], kf, acc, 0, 0, 0);
      }
      sfr[nf] = acc;
    }

    bool diag = (t == qb);
    float mtile[4];
    #pragma unroll
    for (int r = 0; r < 4; ++r) mtile[r] = -1e30f;
    #pragma unroll
    for (int nf = 0; nf < 4; ++nf)
      #pragma unroll
      for (int r = 0; r < 4; ++r) {
        if (diag) {
          int kvg = kv0 + nf * 16 + fr;
          int qg = q0w + 4 * g + r;
          if (kvg > qg) sfr[nf][r] = -1e30f;
        }
        mtile[r] = fmaxf(mtile[r], sfr[nf][r]);
      }
    #pragma unroll
    for (int r = 0; r < 4; ++r) {
      float mv = mtile[r];
      mv = fmaxf(mv, __shfl_xor(mv, 1));
      mv = fmaxf(mv, __shfl_xor(mv, 2));
      mv = fmaxf(mv, __shfl_xor(mv, 4));
      mv = fmaxf(mv, __shfl_xor(mv, 8));
      mtile[r] = mv;
    }
    float alpha[4];
    #pragma unroll
    for (int r = 0; r < 4; ++r) {
      float m_new = fmaxf(m_run[r], mtile[r]);
      alpha[r] = exp2f((m_run[r] - m_new) * sc);
      m_run[r] = m_new;
    }
    float lsum[4] = {0.f, 0.f, 0.f, 0.f};
    #pragma unroll
    for (int nf = 0; nf < 4; ++nf)
      #pragma unroll
      for (int r = 0; r < 4; ++r) {
        float p = exp2f((sfr[nf][r] - m_run[r]) * sc);
        sfr[nf][r] = p;
        lsum[r] += p;
      }
    #pragma unroll
    for (int r = 0; r < 4; ++r) {
      float lv = lsum[r];
      lv += __shfl_xor(lv, 1);
      lv += __shfl_xor(lv, 2);
      lv += __shfl_xor(lv, 4);
      lv += __shfl_xor(lv, 8);
      l_run[r] = l_run[r] * alpha[r] + lv;
    }
    #pragma unroll
    for (int nfo = 0; nfo < 8; ++nfo)
      #pragma unroll
      for (int r = 0; r < 4; ++r) o_frag[nfo][r] *= alpha[r];

    #pragma unroll
    for (int nf = 0; nf < 4; ++nf)
      #pragma unroll
      for (int r = 0; r < 4; ++r)
        p_lds[wid][4 * g + r][nf * 16 + fr] = (bf16_t)sfr[nf][r];

    #pragma unroll
    for (int kc2 = 0; kc2 < 2; ++kc2) {
      bf16x8 pf = *(const bf16x8*)&p_lds[wid][fr][kc2 * 32 + g * 8];
      #pragma unroll
      for (int nfo = 0; nfo < 8; ++nfo) {
        bf16x8 vf =
            *(const bf16x8*)&vfl[cur][(nfo * 128 + kc2 * 64 + fr * 4 + g) * 8];
        o_frag[nfo] = __builtin_amdgcn_mfma_f32_16x16x32_bf16(pf, vf, o_frag[nfo], 0, 0, 0);
      }
    }
    BAR();
  }

  #pragma unroll
  for (int nfo = 0; nfo < 8; ++nfo)
    #pragma unroll
    for (int r = 0; r < 4; ++r) {
      int qg = q0w + 4 * g + r;
      float val = o_frag[nfo][r] / l_run[r];
      o[(size_t)qg * (H_ * DH_) + h * DH_ + nfo * 16 + fr] = (bf16_t)val;
    }
}

// ---------------------------------------------------------------- launch -----
extern "C" void kernel_launch(void* const* d_in, const int* in_sizes, int n_in,
                              void* d_out, int out_size, void* d_ws,
                              size_t ws_size, hipStream_t stream) {
  const float* x = (const float*)d_in[0];
  const int* pos = (const int*)d_in[1];
  const float* ln_w = (const float*)d_in[2];
  const float* ffln_w = (const float*)d_in[3];
  const float* wq = (const float*)d_in[4];
  const float* wk = (const float*)d_in[5];
  const float* wv = (const float*)d_in[6];
  const float* wo = (const float*)d_in[7];
  const float* wg = (const float*)d_in[8];
  const float* w1 = (const float*)d_in[9];
  const float* w2 = (const float*)d_in[10];

  char* ws = (char*)d_ws;
  size_t off = 0;
  auto alloc = [&](size_t bytes) {
    size_t o = off;
    off = (off + bytes + 255) & ~(size_t)255;
    return o;
  };
  bf16_t* Wbuf = (bf16_t*)(ws + alloc((size_t)GU_N * D_ * 2));  // ~172MB shared
  bf16_t* nbuf = (bf16_t*)(ws + alloc((size_t)S_ * D_ * 2));    // a / attn / b
  bf16_t* qkv  = (bf16_t*)(ws + alloc((size_t)S_ * QKV_N * 2));
  float*  x1   = (float*)(ws + alloc((size_t)S_ * D_ * 4));
  bf16_t* h    = (bf16_t*)(ws + alloc((size_t)S_ * HID_ * 2));  // silu(g)*u
  bf16_t* vtb  = (bf16_t*)(ws + alloc((size_t)KVH_ * DH_ * S_ * 2));  // 4MB
  float*  cos_t = (float*)(ws + alloc((size_t)S_ * 64 * 4));
  float*  sin_t = (float*)(ws + alloc((size_t)S_ * 64 * 4));
  // split-K partial buffers in the unused tail of Wbuf: partials (96..160MB)
  // only live while weights <= 90MB (wo / w2); wg|w1's 180MB never coexists.
  float* part = (float*)((char*)Wbuf + ((size_t)96 << 20));  // 2 x 32MB

  // 1. a = rmsnorm(x)
  rmsnorm_kernel<<<S_, 256, 0, stream>>>(x, ln_w, nbuf);
  // 2. W_qkv^T (bf16): rows 0..4095=wq^T, 4096..5119=wk^T, 5120..6143=wv^T
  wtrans_kernel<<<dim3(D_ / 32, D_ / 256), 256, 0, stream>>>(
      wq, Wbuf, D_, D_, 1, 0);
  wtrans_kernel<<<dim3(D_ / 32, 1024 / 256), 256, 0, stream>>>(
      wk, Wbuf + (size_t)4096 * D_, D_, 1024, 1, 0);
  wtrans_kernel<<<dim3(D_ / 32, 1024 / 256), 256, 0, stream>>>(
      wv, Wbuf + (size_t)5120 * D_, D_, 1024, 1, 0);
  rope_table_kernel<<<(S_ * 64) / 256, 256, 0, stream>>>(pos, cos_t, sin_t);
  // 3. qkv = a @ Wqkv with fused RoPE on q,k columns
  gemm256_kernel<3, 0><<<dim3((S_ / 256) * (QKV_N / 256)), 1024, 0, stream>>>(
      nbuf, D_, Wbuf, D_, qkv, QKV_N, D_, cos_t, sin_t);
  // 4. V^T
  vtrans_kernel<<<dim3(S_ / 64, (KVH_ * DH_) / 64), 256, 0, stream>>>(qkv, vtb);
  // 5. attention -> nbuf
  attn_kernel<<<dim3(S_ / 64, H_), 256, 0, stream>>>(qkv, vtb, nbuf);
  // 6. partials = attn @ wo (split-K 2x2048, 256 blocks)
  wtrans_kernel<<<dim3(D_ / 32, D_ / 256), 256, 0, stream>>>(
      wo, Wbuf, D_, D_, 1, 0);
  gemm256_kernel<2, 1><<<dim3((S_ / 256) * (D_ / 256) * 2), 1024, 0, stream>>>(
      nbuf, D_, Wbuf, D_, part, D_, 2048, nullptr, nullptr);
  // 7. x1 = x + p0 + p1 ; b = rmsnorm(x1)
  combine_rms_kernel<<<S_, 256, 0, stream>>>(
      x, part, part + (size_t)S_ * D_, ffln_w, x1, nbuf);
  // 8. h = silu(b@wg) * (b@w1), interleaved weights + fused epilogue
  wtrans_kernel<<<dim3(D_ / 32, HID_ / 256), 256, 0, stream>>>(
      wg, Wbuf, D_, HID_, 2, 0);
  wtrans_kernel<<<dim3(D_ / 32, HID_ / 256), 256, 0, stream>>>(
      w1, Wbuf, D_, HID_, 2, 1);
  gemm256_kernel<4, 0><<<dim3((S_ / 256) * (GU_N / 256)), 1024, 0, stream>>>(
      nbuf, D_, Wbuf, D_, h, HID_, D_, nullptr, nullptr);
  // 9. partials = h @ w2 (split-K 2x5504, 256 blocks)
  wtrans_kernel<<<dim3(HID_ / 32, D_ / 256), 256, 0, stream>>>(
      w2, Wbuf, HID_, D_, 1, 0);
  gemm256_kernel<2, 1><<<dim3((S_ / 256) * (D_ / 256) * 2), 1024, 0, stream>>>(
      h, HID_, Wbuf, HID_, part, D_, 5504, nullptr, nullptr);
  // 10. out = x1 + p0 + p1
  combine_out_kernel<<<(S_ * D_ / 4) / 256, 256, 0, stream>>>(
      x1, part, part + (size_t)S_ * D_, (float*)d_out);
}

// Round 17
// 1175.812 us; speedup vs baseline: 1.0345x; 1.0055x over previous
//
#include <hip/hip_runtime.h>
#include <hip/hip_bf16.h>

typedef __bf16 bf16_t;
typedef __bf16 bf16x2 __attribute__((ext_vector_type(2)));
typedef __bf16 bf16x4 __attribute__((ext_vector_type(4)));
typedef __bf16 bf16x8 __attribute__((ext_vector_type(8)));
typedef float f32x4 __attribute__((ext_vector_type(4)));

#define S_ 2048
#define D_ 4096
#define H_ 32
#define KVH_ 8
#define DH_ 128
#define HID_ 11008
#define QKV_N 6144   // 4096 q + 1024 k + 1024 v
#define GU_N 22016   // interleaved: row 2c = wg^T col c, row 2c+1 = w1^T col c

__device__ __forceinline__ void gl16(const bf16_t* g, bf16_t* l) {
  __builtin_amdgcn_global_load_lds(
      (const __attribute__((address_space(1))) unsigned int*)g,
      (__attribute__((address_space(3))) unsigned int*)l, 16, 0, 0);
}

#define VMW(N)                                          \
  asm volatile("s_waitcnt vmcnt(" #N ")" ::: "memory"); \
  __builtin_amdgcn_sched_barrier(0)

#define LGKM(N)                                           \
  asm volatile("s_waitcnt lgkmcnt(" #N ")" ::: "memory"); \
  __builtin_amdgcn_sched_barrier(0)

#define SB() __builtin_amdgcn_sched_barrier(0)

#define BAR()                          \
  asm volatile("" ::: "memory");       \
  __builtin_amdgcn_s_barrier();        \
  asm volatile("" ::: "memory")

// ---------------------------------------------------------------- RMSNorm ----
__global__ __launch_bounds__(256) void rmsnorm_kernel(
    const float* __restrict__ x, const float* __restrict__ w,
    bf16_t* __restrict__ out) {
  int row = blockIdx.x;
  const float* xr = x + (size_t)row * D_;
  float ss = 0.f;
  #pragma unroll
  for (int it = 0; it < 4; ++it) {
    int i = threadIdx.x * 4 + it * 1024;
    float4 v = *(const float4*)(xr + i);
    ss += v.x * v.x + v.y * v.y + v.z * v.z + v.w * v.w;
  }
  #pragma unroll
  for (int off = 32; off; off >>= 1) ss += __shfl_xor(ss, off);
  __shared__ float s4[4];
  if ((threadIdx.x & 63) == 0) s4[threadIdx.x >> 6] = ss;
  __syncthreads();
  float tot = s4[0] + s4[1] + s4[2] + s4[3];
  float rinv = rsqrtf(tot / (float)D_ + 1e-5f);
  bf16_t* orow = out + (size_t)row * D_;
  #pragma unroll
  for (int it = 0; it < 4; ++it) {
    int i = threadIdx.x * 4 + it * 1024;
    float4 v = *(const float4*)(xr + i);
    orow[i + 0] = (bf16_t)(v.x * rinv * w[i + 0]);
    orow[i + 1] = (bf16_t)(v.y * rinv * w[i + 1]);
    orow[i + 2] = (bf16_t)(v.z * rinv * w[i + 2]);
    orow[i + 3] = (bf16_t)(v.w * rinv * w[i + 3]);
  }
}

// ----------------------- combine wo-partials + residual + RMSNorm ------------
__global__ __launch_bounds__(256) void combine_rms_kernel(
    const float* __restrict__ x, const float* __restrict__ p0,
    const float* __restrict__ p1, const float* __restrict__ w,
    float* __restrict__ x1, bf16_t* __restrict__ out) {
  int row = blockIdx.x;
  size_t base = (size_t)row * D_;
  float ss = 0.f;
  float4 vals[4];
  #pragma unroll
  for (int it = 0; it < 4; ++it) {
    int i = threadIdx.x * 4 + it * 1024;
    float4 a = *(const float4*)(x + base + i);
    float4 b = *(const float4*)(p0 + base + i);
    float4 c = *(const float4*)(p1 + base + i);
    float4 v;
    v.x = a.x + b.x + c.x; v.y = a.y + b.y + c.y;
    v.z = a.z + b.z + c.z; v.w = a.w + b.w + c.w;
    vals[it] = v;
    *(float4*)(x1 + base + i) = v;
    ss += v.x * v.x + v.y * v.y + v.z * v.z + v.w * v.w;
  }
  #pragma unroll
  for (int off = 32; off; off >>= 1) ss += __shfl_xor(ss, off);
  __shared__ float s4[4];
  if ((threadIdx.x & 63) == 0) s4[threadIdx.x >> 6] = ss;
  __syncthreads();
  float tot = s4[0] + s4[1] + s4[2] + s4[3];
  float rinv = rsqrtf(tot / (float)D_ + 1e-5f);
  #pragma unroll
  for (int it = 0; it < 4; ++it) {
    int i = threadIdx.x * 4 + it * 1024;
    float4 v = vals[it];
    out[base + i + 0] = (bf16_t)(v.x * rinv * w[i + 0]);
    out[base + i + 1] = (bf16_t)(v.y * rinv * w[i + 1]);
    out[base + i + 2] = (bf16_t)(v.z * rinv * w[i + 2]);
    out[base + i + 3] = (bf16_t)(v.w * rinv * w[i + 3]);
  }
}

// ----------------------------- combine w2-partials + residual -> d_out -------
__global__ __launch_bounds__(256) void combine_out_kernel(
    const float* __restrict__ x1, const float* __restrict__ p0,
    const float* __restrict__ p1, float* __restrict__ outp) {
  size_t i = ((size_t)blockIdx.x * 256 + threadIdx.x) * 4;
  float4 a = *(const float4*)(x1 + i);
  float4 b = *(const float4*)(p0 + i);
  float4 c = *(const float4*)(p1 + i);
  float4 v;
  v.x = a.x + b.x + c.x; v.y = a.y + b.y + c.y;
  v.z = a.z + b.z + c.z; v.w = a.w + b.w + c.w;
  *(float4*)(outp + i) = v;
}

// ------------------------------------------- weight transpose f32 -> bf16 ----
// out row index = (n0+nn)*rstride + roff  (rstride=2 interleaves wg/w1)
// r17: LDS writes as paired bf16x2 (explicit b32 stores; compiler could not
// merge the 4 scalar u16 stores since row stride 516B only proves 4B align).
// Read side unchanged: [32][258] keeps the column-gather reads conflict-free.
__global__ __launch_bounds__(256) void wtrans_kernel(
    const float* __restrict__ W, bf16_t* __restrict__ WT, int K, int N,
    int rstride, int roff) {
  __shared__ bf16_t t[32][258];
  int k0 = blockIdx.x * 32, n0 = blockIdx.y * 256;
  #pragma unroll
  for (int i = 0; i < 8; ++i) {
    int flat = i * 1024 + threadIdx.x * 4;
    int kk = flat >> 8, nn = flat & 255;
    float4 wv = *(const float4*)(W + (size_t)(k0 + kk) * N + n0 + nn);
    bf16x2 lo, hi;
    lo[0] = (bf16_t)wv.x; lo[1] = (bf16_t)wv.y;
    hi[0] = (bf16_t)wv.z; hi[1] = (bf16_t)wv.w;
    *(bf16x2*)&t[kk][nn] = lo;
    *(bf16x2*)&t[kk][nn + 2] = hi;
  }
  __syncthreads();
  int kc8 = (threadIdx.x & 3) * 8;
  #pragma unroll
  for (int i = 0; i < 4; ++i) {
    int nn = i * 64 + (threadIdx.x >> 2);
    bf16x8 vals;
    #pragma unroll
    for (int j = 0; j < 8; ++j) vals[j] = t[kc8 + j][nn];
    *(bf16x8*)(WT + ((size_t)(n0 + nn) * rstride + roff) * K + k0 + kc8) = vals;
  }
}

// ------------------------------------- V transpose: qkv v-part -> vt[d][s] ---
__global__ __launch_bounds__(256) void vtrans_kernel(
    const bf16_t* __restrict__ qkv, bf16_t* __restrict__ vt) {
  __shared__ bf16_t t[64][72];
  int s0 = blockIdx.x * 64, d0 = blockIdx.y * 64;
  #pragma unroll
  for (int it = 0; it < 2; ++it) {
    int r = (threadIdx.x >> 3) + it * 32;
    int c = (threadIdx.x & 7) * 8;
    *(bf16x8*)&t[r][c] =
        *(const bf16x8*)(qkv + (size_t)(s0 + r) * QKV_N + 5120 + d0 + c);
  }
  __syncthreads();
  #pragma unroll
  for (int it = 0; it < 2; ++it) {
    int c = threadIdx.x & 63;
    int sb = (threadIdx.x >> 6) * 16 + it * 8;
    bf16x8 v;
    #pragma unroll
    for (int j = 0; j < 8; ++j) v[j] = t[sb + j][c];
    *(bf16x8*)(vt + (size_t)(d0 + c) * S_ + s0 + sb) = v;
  }
}

// ------------------------------------------------------------- RoPE table ----
__global__ __launch_bounds__(256) void rope_table_kernel(
    const int* __restrict__ pos_ids, float* __restrict__ cos_t,
    float* __restrict__ sin_t) {
  int idx = blockIdx.x * 256 + threadIdx.x;  // S_*64
  int s = idx >> 6, i = idx & 63;
  float pos = (float)pos_ids[s];
  float inv_freq = exp2f(-(float)i * (13.287712379549449f / 64.0f));
  float ang = pos * inv_freq;
  cos_t[idx] = cosf(ang);
  sin_t[idx] = sinf(ang);
}

// ------------------------------------------------------- 256x256 GEMM --------
// C[2048][N] = A[2048][K+] (bf16) @ BT[N][K+] (bf16)
// MODE 0: bf16 out
// MODE 2: f32 plain store (SPLIT partials)
// MODE 3: bf16 out + fused RoPE on cols < 5120 (qkv; pairs = adjacent fr lanes)
// MODE 4: fused silu(g)*u from interleaved gu cols; even lanes store h[col>>1]
// r11 structure: 1024 thr, 16 waves (4Mx4N), 64x64/wave, BK=64, dbuf,
// 1 barrier + VMW(0)/tile, zero-conflict chunk-rotation LDS.
// NOTE (r8): no extra fragment register sets — they spill. (r10/r12: barrier
// thinning and lgkmcnt group pipelines = null; LDS-fragment BW and MFMA are
// co-dominant at this tile geometry — GEMM plateau ~45% MfmaUtil.)

#define READ_A(dst, BIx, KK)                                               \
  _Pragma("unroll") for (int m = 0; m < 4; ++m)                            \
    dst[m] = *(const bf16x8*)&lds[BIx][0][KK]                              \
        [(wr * 64 + m * 16 + fr) * 32 + rc * 8];

#define READ_B(dst, BIx, KK)                                               \
  _Pragma("unroll") for (int n = 0; n < 4; ++n)                            \
    dst[n] = *(const bf16x8*)&lds[BIx][1][KK]                              \
        [(wc * 64 + n * 16 + fr) * 32 + rc * 8];

#define MFMA16(aS, bS)                                                     \
  __builtin_amdgcn_s_setprio(1);                                           \
  _Pragma("unroll") for (int m = 0; m < 4; ++m)                            \
    _Pragma("unroll") for (int n = 0; n < 4; ++n)                          \
      acc[m][n] = __builtin_amdgcn_mfma_f32_16x16x32_bf16(                 \
          aS[m], bS[n], acc[m][n], 0, 0, 0);                               \
  __builtin_amdgcn_s_setprio(0);

template <int MODE, int SPLIT>
__global__ __launch_bounds__(1024, 4) void gemm256_kernel(
    const bf16_t* __restrict__ A, int lda, const bf16_t* __restrict__ BT,
    int ldb, void* __restrict__ Cout, int ldc, int K,
    const float* __restrict__ cosT, const float* __restrict__ sinT) {
  // [buf][A=0/B=1][kk][256 rows * 32 elems] = 128 KiB
  __shared__ __align__(16) bf16_t lds[2][2][2][256 * 32];

  const int tid = threadIdx.x;
  const int lane = tid & 63;
  const int wid = tid >> 6;           // 0..15
  const int wr = wid >> 2;            // 0..3 (M quarter)
  const int wc = wid & 3;             // 0..3 (N quarter)
  const int g = lane >> 4, fr = lane & 15;
  const int rc = (g + ((fr >> 1) & 3)) & 3;   // rotated read-chunk slot

  const int nwg = gridDim.x;
  const int orig = blockIdx.x;
  int wg = (orig & 7) * (nwg >> 3) + (orig >> 3);
  int kz = 0;
  if constexpr (SPLIT) {
    const int half = nwg >> 1;
    kz = wg >= half;
    wg -= kz * half;
  }
  const int bx = wg & 7;
  const int by = wg >> 3;
  const size_t row0 = (size_t)bx * 256, col0 = (size_t)by * 256;

  // staging: row-linear source, chunk rotated by (row>>1); row = tid>>2 (0..255)
  const int srow = tid >> 2;
  const int schunk = ((tid & 3) - ((tid >> 3) & 3)) & 3;

  const size_t lda2 = (size_t)lda * 2, ldb2 = (size_t)ldb * 2;
  const size_t kzoff = (size_t)kz * K * 2;
  const char* aB =
      (const char*)A + (row0 + srow) * lda2 + schunk * 16 + kzoff;
  const char* bB =
      (const char*)BT + (col0 + srow) * ldb2 + schunk * 16 + kzoff;

  auto stage = [&](int bi, int ab, int kk, int kt) {
    const char* base = ab ? bB : aB;
    gl16((const bf16_t*)(base + (size_t)kt * 128 + kk * 64),
         &lds[bi][ab][kk][tid * 8]);
  };

  f32x4 acc[4][4] = {};
  bf16x8 aF[4], bF[4];
  const int NT = K / 64;

  // prologue: tile0 -> buf0
  stage(0, 0, 0, 0); stage(0, 1, 0, 0);
  stage(0, 0, 1, 0); stage(0, 1, 1, 0);
  VMW(0);
  BAR();

  for (int T = 0; T < NT; ++T) {
    const int BI = T & 1;
    const int Tp1 = T + 1 < NT;
    if (Tp1) {  // next tile -> other buffer; readers finished at T-1's barrier
      stage(BI ^ 1, 0, 0, T + 1); stage(BI ^ 1, 1, 0, T + 1);
      stage(BI ^ 1, 0, 1, T + 1); stage(BI ^ 1, 1, 1, T + 1);
    }
    READ_A(aF, BI, 0); READ_B(bF, BI, 0);
    LGKM(0);
    MFMA16(aF, bF);
    READ_A(aF, BI, 1); READ_B(bF, BI, 1);
    LGKM(0);
    MFMA16(aF, bF);
    VMW(0);   // T+1's 4 loads resident (issued a full tile of compute ago)
    BAR();
  }

  // epilogue
  float* fOut = (float*)Cout + (size_t)kz * 2048 * ldc;
  #pragma unroll
  for (int m = 0; m < 4; ++m)
    #pragma unroll
    for (int n = 0; n < 4; ++n)
      #pragma unroll
      for (int r = 0; r < 4; ++r) {
        size_t row = row0 + wr * 64 + m * 16 + g * 4 + r;
        size_t col = col0 + wc * 64 + n * 16 + fr;
        float val = acc[m][n][r];
        if constexpr (MODE == 0) {
          ((bf16_t*)Cout)[row * ldc + col] = (bf16_t)val;
        } else if constexpr (MODE == 2) {
          fOut[row * ldc + col] = val;
        } else if constexpr (MODE == 3) {
          // fused RoPE: pairs (2i,2i+1) are adjacent fr lanes
          float p = __shfl_xor(val, 1);
          if ((int)col < 5120) {
            int i = ((int)col & 127) >> 1;
            float c = cosT[row * 64 + i], s = sinT[row * 64 + i];
            val = (fr & 1) ? (p * s + val * c) : (val * c - p * s);
          }
          ((bf16_t*)Cout)[row * ldc + col] = (bf16_t)val;
        } else {
          // MODE 4: interleaved gu -> h = silu(g)*u, even lanes store col>>1
          float p = __shfl_xor(val, 1);
          if (!(fr & 1)) {
            float gv = val;
            float hv = gv / (1.f + __expf(-gv)) * p;
            ((bf16_t*)Cout)[row * ldc + (col >> 1)] = (bf16_t)hv;
          }
        }
      }
}

// ------------------------------------------------------- flash attention -----
// grid (32 qb, 32 h), 4 waves. K and V^T staged via global_load_lds into
// lane-ordered fragment blocks (zero-conflict ds_read_b128), double-buffered
// with counted vmcnt(8). V^T comes from the pre-transposed vt buffer.
__global__ __launch_bounds__(256, 2) void attn_kernel(
    const bf16_t* __restrict__ qkv, const bf16_t* __restrict__ vt,
    bf16_t* __restrict__ o) {
  int h = blockIdx.y;
  int qb = (S_ / 64 - 1) - blockIdx.x;  // longest blocks dispatch first
  int kvh = h >> 2;
  int tid = threadIdx.x;
  int wid = tid >> 6, lane = tid & 63;
  int g = lane >> 4, fr = lane & 15;

  __shared__ __align__(16) bf16_t kfl[2][8192];
  __shared__ __align__(16) bf16_t vfl[2][8192];
  __shared__ __align__(16) bf16_t p_lds[4][16][72];

  const int fr_s = (tid >> 2) & 15, g_s = tid & 3;
  const int kcw = (tid >> 6) & 3;
  const int kc2w = (tid >> 6) & 1;
  const int nhi = tid >> 7;
  const bf16_t* kSrc = qkv + (size_t)fr_s * QKV_N + 4096 + kvh * 128 +
                       (kcw * 4 + g_s) * 8;
  const bf16_t* vSrc = vt + ((size_t)kvh * 128 + nhi * 16 + fr_s) * S_ +
                       (kc2w * 4 + g_s) * 8;

  auto stage = [&](int bi, int t) {
    size_t kv0 = (size_t)t * 64;
    #pragma unroll
    for (int i = 0; i < 4; ++i)
      gl16(kSrc + (kv0 + i * 16) * QKV_N, &kfl[bi][(i * 256 + tid) * 8]);
    #pragma unroll
    for (int i = 0; i < 4; ++i)
      gl16(vSrc + (size_t)i * 32 * S_ + kv0, &vfl[bi][(i * 256 + tid) * 8]);
  };

  int q0w = qb * 64 + wid * 16;
  bf16x8 q_frag[4];
  const bf16_t* qptr = qkv + (size_t)(q0w + fr) * QKV_N + h * 128;
  #pragma unroll
  for (int kc = 0; kc < 4; ++kc)
    q_frag[kc] = *(const bf16x8*)(qptr + kc * 32 + g * 8);
  VMW(0);  // q_frag landed; keep manual vmcnt accounting exact

  stage(0, 0);

  f32x4 o_frag[8] = {};
  float m_run[4], l_run[4];
  #pragma unroll
  for (int r = 0; r < 4; ++r) { m_run[r] = -1e30f; l_run[r] = 0.f; }

  const float sc = 0.08838834764831845f * 1.4426950408889634f;

  for (int t = 0; t <= qb; ++t) {
    int cur = t & 1;
    int kv0 = t * 64;
    if (t < qb) {
      stage(cur ^ 1, t + 1);
      VMW(8);
    } else {
      VMW(0);
    }
    BAR();

    f32x4 sfr[4];
    #pragma unroll
    for (int nf = 0; nf < 4; ++nf) {
      f32x4 acc = {};
      #pragma unroll
      for (int kc = 0; kc < 4; ++kc) {
        bf16x8 kf =
            *(const bf16x8*)&kfl[cur][(nf * 256 + kc * 64 + fr * 4 + g) * 8];
        acc = __builtin_amdgcn_mfma_f32_16x16x32_bf16(q_frag[kc], kf, acc, 0, 0, 0);
      }
      sfr[nf] = acc;
    }

    bool diag = (t == qb);
    float mtile[4];
    #pragma unroll
    for (int r = 0; r < 4; ++r) mtile[r] = -1e30f;
    #pragma unroll
    for (int nf = 0; nf < 4; ++nf)
      #pragma unroll
      for (int r = 0; r < 4; ++r) {
        if (diag) {
          int kvg = kv0 + nf * 16 + fr;
          int qg = q0w + 4 * g + r;
          if (kvg > qg) sfr[nf][r] = -1e30f;
        }
        mtile[r] = fmaxf(mtile[r], sfr[nf][r]);
      }
    #pragma unroll
    for (int r = 0; r < 4; ++r) {
      float mv = mtile[r];
      mv = fmaxf(mv, __shfl_xor(mv, 1));
      mv = fmaxf(mv, __shfl_xor(mv, 2));
      mv = fmaxf(mv, __shfl_xor(mv, 4));
      mv = fmaxf(mv, __shfl_xor(mv, 8));
      mtile[r] = mv;
    }
    float alpha[4];
    #pragma unroll
    for (int r = 0; r < 4; ++r) {
      float m_new = fmaxf(m_run[r], mtile[r]);
      alpha[r] = exp2f((m_run[r] - m_new) * sc);
      m_run[r] = m_new;
    }
    float lsum[4] = {0.f, 0.f, 0.f, 0.f};
    #pragma unroll
    for (int nf = 0; nf < 4; ++nf)
      #pragma unroll
      for (int r = 0; r < 4; ++r) {
        float p = exp2f((sfr[nf][r] - m_run[r]) * sc);
        sfr[nf][r] = p;
        lsum[r] += p;
      }
    #pragma unroll
    for (int r = 0; r < 4; ++r) {
      float lv = lsum[r];
      lv += __shfl_xor(lv, 1);
      lv += __shfl_xor(lv, 2);
      lv += __shfl_xor(lv, 4);
      lv += __shfl_xor(lv, 8);
      l_run[r] = l_run[r] * alpha[r] + lv;
    }
    #pragma unroll
    for (int nfo = 0; nfo < 8; ++nfo)
      #pragma unroll
      for (int r = 0; r < 4; ++r) o_frag[nfo][r] *= alpha[r];

    #pragma unroll
    for (int nf = 0; nf < 4; ++nf)
      #pragma unroll
      for (int r = 0; r < 4; ++r)
        p_lds[wid][4 * g + r][nf * 16 + fr] = (bf16_t)sfr[nf][r];

    #pragma unroll
    for (int kc2 = 0; kc2 < 2; ++kc2) {
      bf16x8 pf = *(const bf16x8*)&p_lds[wid][fr][kc2 * 32 + g * 8];
      #pragma unroll
      for (int nfo = 0; nfo < 8; ++nfo) {
        bf16x8 vf =
            *(const bf16x8*)&vfl[cur][(nfo * 128 + kc2 * 64 + fr * 4 + g) * 8];
        o_frag[nfo] = __builtin_amdgcn_mfma_f32_16x16x32_bf16(pf, vf, o_frag[nfo], 0, 0, 0);
      }
    }
    BAR();
  }

  #pragma unroll
  for (int nfo = 0; nfo < 8; ++nfo)
    #pragma unroll
    for (int r = 0; r < 4; ++r) {
      int qg = q0w + 4 * g + r;
      float val = o_frag[nfo][r] / l_run[r];
      o[(size_t)qg * (H_ * DH_) + h * DH_ + nfo * 16 + fr] = (bf16_t)val;
    }
}

// ---------------------------------------------------------------- launch -----
extern "C" void kernel_launch(void* const* d_in, const int* in_sizes, int n_in,
                              void* d_out, int out_size, void* d_ws,
                              size_t ws_size, hipStream_t stream) {
  const float* x = (const float*)d_in[0];
  const int* pos = (const int*)d_in[1];
  const float* ln_w = (const float*)d_in[2];
  const float* ffln_w = (const float*)d_in[3];
  const float* wq = (const float*)d_in[4];
  const float* wk = (const float*)d_in[5];
  const float* wv = (const float*)d_in[6];
  const float* wo = (const float*)d_in[7];
  const float* wg = (const float*)d_in[8];
  const float* w1 = (const float*)d_in[9];
  const float* w2 = (const float*)d_in[10];

  char* ws = (char*)d_ws;
  size_t off = 0;
  auto alloc = [&](size_t bytes) {
    size_t o = off;
    off = (off + bytes + 255) & ~(size_t)255;
    return o;
  };
  bf16_t* Wbuf = (bf16_t*)(ws + alloc((size_t)GU_N * D_ * 2));  // ~172MB shared
  bf16_t* nbuf = (bf16_t*)(ws + alloc((size_t)S_ * D_ * 2));    // a / attn / b
  bf16_t* qkv  = (bf16_t*)(ws + alloc((size_t)S_ * QKV_N * 2));
  float*  x1   = (float*)(ws + alloc((size_t)S_ * D_ * 4));
  bf16_t* h    = (bf16_t*)(ws + alloc((size_t)S_ * HID_ * 2));  // silu(g)*u
  bf16_t* vtb  = (bf16_t*)(ws + alloc((size_t)KVH_ * DH_ * S_ * 2));  // 4MB
  float*  cos_t = (float*)(ws + alloc((size_t)S_ * 64 * 4));
  float*  sin_t = (float*)(ws + alloc((size_t)S_ * 64 * 4));
  // split-K partial buffers in the unused tail of Wbuf: partials (96..160MB)
  // only live while weights <= 90MB (wo / w2); wg|w1's 180MB never coexists.
  float* part = (float*)((char*)Wbuf + ((size_t)96 << 20));  // 2 x 32MB

  // 1. a = rmsnorm(x)
  rmsnorm_kernel<<<S_, 256, 0, stream>>>(x, ln_w, nbuf);
  // 2. W_qkv^T (bf16): rows 0..4095=wq^T, 4096..5119=wk^T, 5120..6143=wv^T
  wtrans_kernel<<<dim3(D_ / 32, D_ / 256), 256, 0, stream>>>(
      wq, Wbuf, D_, D_, 1, 0);
  wtrans_kernel<<<dim3(D_ / 32, 1024 / 256), 256, 0, stream>>>(
      wk, Wbuf + (size_t)4096 * D_, D_, 1024, 1, 0);
  wtrans_kernel<<<dim3(D_ / 32, 1024 / 256), 256, 0, stream>>>(
      wv, Wbuf + (size_t)5120 * D_, D_, 1024, 1, 0);
  rope_table_kernel<<<(S_ * 64) / 256, 256, 0, stream>>>(pos, cos_t, sin_t);
  // 3. qkv = a @ Wqkv with fused RoPE on q,k columns
  gemm256_kernel<3, 0><<<dim3((S_ / 256) * (QKV_N / 256)), 1024, 0, stream>>>(
      nbuf, D_, Wbuf, D_, qkv, QKV_N, D_, cos_t, sin_t);
  // 4. V^T
  vtrans_kernel<<<dim3(S_ / 64, (KVH_ * DH_) / 64), 256, 0, stream>>>(qkv, vtb);
  // 5. attention -> nbuf
  attn_kernel<<<dim3(S_ / 64, H_), 256, 0, stream>>>(qkv, vtb, nbuf);
  // 6. partials = attn @ wo (split-K 2x2048, 256 blocks)
  wtrans_kernel<<<dim3(D_ / 32, D_ / 256), 256, 0, stream>>>(
      wo, Wbuf, D_, D_, 1, 0);
  gemm256_kernel<2, 1><<<dim3((S_ / 256) * (D_ / 256) * 2), 1024, 0, stream>>>(
      nbuf, D_, Wbuf, D_, part, D_, 2048, nullptr, nullptr);
  // 7. x1 = x + p0 + p1 ; b = rmsnorm(x1)
  combine_rms_kernel<<<S_, 256, 0, stream>>>(
      x, part, part + (size_t)S_ * D_, ffln_w, x1, nbuf);
  // 8. h = silu(b@wg) * (b@w1), interleaved weights + fused epilogue
  wtrans_kernel<<<dim3(D_ / 32, HID_ / 256), 256, 0, stream>>>(
      wg, Wbuf, D_, HID_, 2, 0);
  wtrans_kernel<<<dim3(D_ / 32, HID_ / 256), 256, 0, stream>>>(
      w1, Wbuf, D_, HID_, 2, 1);
  gemm256_kernel<4, 0><<<dim3((S_ / 256) * (GU_N / 256)), 1024, 0, stream>>>(
      nbuf, D_, Wbuf, D_, h, HID_, D_, nullptr, nullptr);
  // 9. partials = h @ w2 (split-K 2x5504, 256 blocks)
  wtrans_kernel<<<dim3(HID_ / 32, D_ / 256), 256, 0, stream>>>(
      w2, Wbuf, HID_, D_, 1, 0);
  gemm256_kernel<2, 1><<<dim3((S_ / 256) * (D_ / 256) * 2), 1024, 0, stream>>>(
      h, HID_, Wbuf, HID_, part, D_, 5504, nullptr, nullptr);
  // 10. out = x1 + p0 + p1
  combine_out_kernel<<<(S_ * D_ / 4) / 256, 256, 0, stream>>>(
      x1, part, part + (size_t)S_ * D_, (float*)d_out);
}